// Round 10
// baseline (186.310 us; speedup 1.0000x reference)
//
#include <hip/hip_runtime.h>
#include <math.h>

// ---------------------------------------------------------------------------
// B=4, S=8192, D=1024, H=4, hd=256.
// Lattice positions {12,36,104,304,888,2592,7568}; 16 entries level-major
// (rows = e*4+b: L1 0..27, L2 28..51, L3 52..63).
//
// 9 kernels, stream-ordered (round-8 structure). Surplus blocks in every
// kernel copy a static slice of x->out (plain loads keep x L3-warm;
// nontemporal stores; skip the 28 chain-written rows).
// GEMMs: A[4][8] proven shape (VGPR~64). NEW vs round 8: each block owns ONE
// j-tile and LOOPS over row chunks, so each weight j-slice is HBM-fetched
// once per block (L1/L2-hot for later chunks) -> ~128 MB less HBM traffic.
// ---------------------------------------------------------------------------

#define SEQ 8192
#define DM  1024

typedef float fx4 __attribute__((ext_vector_type(4)));

__device__ __constant__ int c_nodes[16][3] = {
  {0,2,4},{2,4,12},{4,12,36},{12,36,104},{36,104,304},{104,304,888},{304,888,2592},
  {0,0,0},{0,2,0},{0,2,4},{2,4,12},{4,12,36},{12,36,104},
  {0,0,0},{0,2,0},{0,2,4}};
__device__ __constant__ float c_wt[16][3] = {
  {1,1,1},{1,1,1},{1,1,1},{1,1,1},{1,1,1},{1,1,1},{1,1,1},
  {1,0,0},{1,1,0},{1,1,1},{1,2,3},{1,2,3},{1,2,3},
  {1,0,0},{1,1,0},{1,1,1}};
__device__ __constant__ float c_winv[16] = {
  1.f/3.f,1.f/3.f,1.f/3.f,1.f/3.f,1.f/3.f,1.f/3.f,1.f/3.f,
  1.f,0.5f,1.f/3.f,1.f/6.f,1.f/6.f,1.f/6.f,
  1.f,0.5f,1.f/3.f};
__device__ __constant__ int c_pos[7]  = {12,36,104,304,888,2592,7568};
__device__ __constant__ int c_ne[7]   = {1,2,2,2,3,3,3};
__device__ __constant__ int c_posE[7][3] = {
  {0,0,0},{1,7,0},{2,8,0},{3,9,0},{4,10,13},{5,11,14},{6,12,15}};

// 8-row chunks of the 64 entry-rows (levels don't cross chunks)
__device__ __constant__ int c_lr0[9]  = {0,8,16,24,28,36,44,52,60};
__device__ __constant__ int c_lnr[9]  = {8,8,8,4,8,8,8,8,4};
__device__ __constant__ int c_or0[4]  = {0,8,16,24};
__device__ __constant__ int c_onr[4]  = {8,8,8,4};

// ---------------------------------------------------------------------------
// copy 4 chunks (16 KB = 4 rows each) at c0; 16 loads in flight; stores
// skip the 28 chain-written rows.
// ---------------------------------------------------------------------------
__device__ __forceinline__ void copy4(const float* __restrict__ x,
                                      float* __restrict__ out, int c0)
{
  const fx4* __restrict__ src4 = (const fx4*)x;
  fx4* __restrict__ dst4 = (fx4*)out;
  const int tid = threadIdx.x;
  fx4 v[16]; size_t idx[16];
#pragma unroll
  for (int u = 0; u < 16; ++u) {
    const int c = c0 + (u >> 2), k = u & 3;
    idx[u] = (size_t)c * 1024 + (size_t)k * 256 + tid;
    v[u] = src4[idx[u]];
  }
#pragma unroll
  for (int u = 0; u < 16; ++u) {
    const int s = ((c0 + (u >> 2)) * 4 + (u & 3)) & (SEQ - 1);
    if (s==12 || s==36 || s==104 || s==304 || s==888 || s==2592 || s==7568)
      continue;
    __builtin_nontemporal_store(v[u], &dst4[idx[u]]);
  }
}

// ---------------------------------------------------------------------------
// GEMM core (proven shape): wave wv owns 4 cols j0..j0+3; 8 rows via
// pointer array; lanes over k (float4); runtime k-loop.
// ---------------------------------------------------------------------------
__device__ __forceinline__ void acc8(float (&A)[4][8],
                                     const float* const (&Xr)[8],
                                     const float* __restrict__ W,
                                     int Wld, int wcol, int j0, int T)
{
  const int lane = threadIdx.x & 63;
  for (int t = 0; t < T; ++t) {
    const int k = t * 256 + lane * 4;
    const float* wp = W + (size_t)j0 * Wld + wcol + k;
    const float4 w0 = *(const float4*)(wp);
    const float4 w1 = *(const float4*)(wp + Wld);
    const float4 w2 = *(const float4*)(wp + 2 * Wld);
    const float4 w3 = *(const float4*)(wp + 3 * Wld);
#pragma unroll
    for (int r = 0; r < 8; ++r) {
      const float4 xv = *(const float4*)(Xr[r] + k);
      A[0][r] += w0.x*xv.x + w0.y*xv.y + w0.z*xv.z + w0.w*xv.w;
      A[1][r] += w1.x*xv.x + w1.y*xv.y + w1.z*xv.z + w1.w*xv.w;
      A[2][r] += w2.x*xv.x + w2.y*xv.y + w2.z*xv.z + w2.w*xv.w;
      A[3][r] += w3.x*xv.x + w3.y*xv.y + w3.z*xv.z + w3.w*xv.w;
    }
  }
}

__device__ __forceinline__ void fin8(float (&A)[4][8],
                                     const float* __restrict__ Bv, int j0,
                                     float* __restrict__ Y, int ldy,
                                     int r0, int nr)
{
  const int lane = threadIdx.x & 63;
#pragma unroll
  for (int r = 0; r < 8; ++r) {
    float v0 = A[0][r], v1 = A[1][r], v2 = A[2][r], v3 = A[3][r];
#pragma unroll
    for (int off = 32; off >= 1; off >>= 1) {
      v0 += __shfl_xor(v0, off); v1 += __shfl_xor(v1, off);
      v2 += __shfl_xor(v2, off); v3 += __shfl_xor(v3, off);
    }
    if (lane == 0 && r < nr) {
      float* yr = Y + (size_t)(r0 + r) * ldy + j0;
      yr[0] = v0 + Bv[j0];     yr[1] = v1 + Bv[j0 + 1];
      yr[2] = v2 + Bv[j0 + 2]; yr[3] = v3 + Bv[j0 + 3];
    }
  }
}

// ---------------------------------------------------------------------------
// K0: F rows (64 blocks; copy chunks [0,1040))
// ---------------------------------------------------------------------------
__global__ __launch_bounds__(256)
void k_feats(const float* __restrict__ x, float* __restrict__ F,
             float* __restrict__ out)
{
  const int bid = blockIdx.x;
  if (bid >= 64) { copy4(x, out, 0 + (bid - 64) * 4); return; }
  const int e = bid >> 2, b = bid & 3;
  const int d = threadIdx.x * 4;
  float4 s = make_float4(0.f, 0.f, 0.f, 0.f);
#pragma unroll
  for (int n = 0; n < 3; ++n) {
    const float w = c_wt[e][n];
    const float4 v = *(const float4*)(x + ((size_t)b*SEQ + c_nodes[e][n])*DM + d);
    s.x += w*v.x; s.y += w*v.y; s.z += w*v.z; s.w += w*v.w;
  }
  const float inv = c_winv[e];
  s.x*=inv; s.y*=inv; s.z*=inv; s.w*=inv;
  *(float4*)(F + (size_t)bid*DM + d) = s;
}

// ---------------------------------------------------------------------------
// K1: H = F @ lt_w1^T + b1 (192 gemm blocks = lvl x 64 jt, chunk-looped;
//     copy [1040,1960))
// ---------------------------------------------------------------------------
__global__ __launch_bounds__(256)
void k_lat1(const float* __restrict__ x, const float* __restrict__ F,
            const float* __restrict__ w1, const float* __restrict__ b1,
            float* __restrict__ Hh, float* __restrict__ out)
{
  const int bid = blockIdx.x;
  if (bid >= 192) { copy4(x, out, 1040 + (bid - 192) * 4); return; }
  const int lvl = bid >> 6, jt = bid & 63;
  const int j0 = jt * 16 + (threadIdx.x >> 6) * 4;
  const float* W = w1 + (size_t)lvl * DM * DM;
  const float* Bv = b1 + lvl * DM;
  const int chlo = (lvl == 0) ? 0 : ((lvl == 1) ? 4 : 7);
  const int chhi = (lvl == 0) ? 4 : ((lvl == 1) ? 7 : 9);
  for (int ch = chlo; ch < chhi; ++ch) {
    const int r0 = c_lr0[ch], nr = c_lnr[ch];
    float A[4][8] = {};
    const float* Xr[8];
#pragma unroll
    for (int r = 0; r < 8; ++r)
      Xr[r] = F + (size_t)(r0 + ((r < nr) ? r : nr - 1)) * DM;
    acc8(A, Xr, W, DM, 0, j0, 4);
    fin8(A, Bv, j0, Hh, DM, r0, nr);
  }
}

// ---------------------------------------------------------------------------
// K2: G = GELU(LN(H)) (64 blocks; copy [1960,3080))
// ---------------------------------------------------------------------------
__global__ __launch_bounds__(256)
void k_ln(const float* __restrict__ x, const float* __restrict__ Hh,
          const float* __restrict__ lng, const float* __restrict__ lnb,
          float* __restrict__ G, float* __restrict__ out)
{
  __shared__ float s1[4], s2[4];
  const int bid = blockIdx.x;
  if (bid >= 64) { copy4(x, out, 1960 + (bid - 64) * 4); return; }
  const int lvl = (bid < 28) ? 0 : ((bid < 52) ? 1 : 2);
  const int j = threadIdx.x * 4;
  const int lane = threadIdx.x & 63, wv = threadIdx.x >> 6;
  const float4 v = *(const float4*)(Hh + (size_t)bid*DM + j);
  float s = v.x+v.y+v.z+v.w;
  float q = v.x*v.x+v.y*v.y+v.z*v.z+v.w*v.w;
#pragma unroll
  for (int off = 32; off >= 1; off >>= 1) {
    s += __shfl_xor(s, off); q += __shfl_xor(q, off);
  }
  if (lane == 0) { s1[wv] = s; s2[wv] = q; }
  __syncthreads();
  const float ts = s1[0]+s1[1]+s1[2]+s1[3];
  const float tq = s2[0]+s2[1]+s2[2]+s2[3];
  const float m = ts * (1.f/1024.f);
  const float rs = rsqrtf(tq * (1.f/1024.f) - m*m + 1e-5f);
  const float4 g4 = *(const float4*)(lng + (size_t)lvl*DM + j);
  const float4 b4 = *(const float4*)(lnb + (size_t)lvl*DM + j);
  const float t0 = (v.x-m)*rs*g4.x + b4.x;
  const float t1 = (v.y-m)*rs*g4.y + b4.y;
  const float t2 = (v.z-m)*rs*g4.z + b4.z;
  const float t3 = (v.w-m)*rs*g4.w + b4.w;
  const float kc = 0.70710678118654752f;
  float4 o;
  o.x = 0.5f*t0*(1.f+erff(t0*kc));
  o.y = 0.5f*t1*(1.f+erff(t1*kc));
  o.z = 0.5f*t2*(1.f+erff(t2*kc));
  o.w = 0.5f*t3*(1.f+erff(t3*kc));
  *(float4*)(G + (size_t)bid*DM + j) = o;
}

// ---------------------------------------------------------------------------
// K3: KV = G @ lt_w2^T + b2 (192 gemm blocks, chunk-looped; copy [3080,4000))
// ---------------------------------------------------------------------------
__global__ __launch_bounds__(256)
void k_lat2(const float* __restrict__ x, const float* __restrict__ G,
            const float* __restrict__ w2, const float* __restrict__ b2,
            float* __restrict__ KV, float* __restrict__ out)
{
  const int bid = blockIdx.x;
  if (bid >= 192) { copy4(x, out, 3080 + (bid - 192) * 4); return; }
  const int lvl = bid >> 6, jt = bid & 63;
  const int j0 = jt * 16 + (threadIdx.x >> 6) * 4;
  const float* W = w2 + (size_t)lvl * DM * DM;
  const float* Bv = b2 + lvl * DM;
  const int chlo = (lvl == 0) ? 0 : ((lvl == 1) ? 4 : 7);
  const int chhi = (lvl == 0) ? 4 : ((lvl == 1) ? 7 : 9);
  for (int ch = chlo; ch < chhi; ++ch) {
    const int r0 = c_lr0[ch], nr = c_lnr[ch];
    float A[4][8] = {};
    const float* Xr[8];
#pragma unroll
    for (int r = 0; r < 8; ++r)
      Xr[r] = G + (size_t)(r0 + ((r < nr) ? r : nr - 1)) * DM;
    acc8(A, Xr, W, DM, 0, j0, 4);
    fin8(A, Bv, j0, KV, DM, r0, nr);
  }
}

// ---------------------------------------------------------------------------
// K4: Q/K/V projections (192 gemm blocks = mat x 64 jt, chunk-looped;
//     copy [4000,4912))
// ---------------------------------------------------------------------------
__global__ __launch_bounds__(256)
void k_qkv(const float* __restrict__ x, const float* __restrict__ KV,
           const float* __restrict__ Wi, const float* __restrict__ Bi,
           float* __restrict__ QH, float* __restrict__ KH,
           float* __restrict__ VH, float* __restrict__ out)
{
  const int bid = blockIdx.x;
  if (bid >= 192) { copy4(x, out, 4000 + (bid - 192) * 4); return; }
  const int mat = bid >> 6, jt = bid & 63;
  const int j0 = jt * 16 + (threadIdx.x >> 6) * 4;
  if (mat == 0) {
    for (int ic = 0; ic < 4; ++ic) {
      const int r0 = c_or0[ic], nr = c_onr[ic];
      float A[4][8] = {};
      const float* Xr[8];
#pragma unroll
      for (int r = 0; r < 8; ++r) {
        const int i = r0 + ((r < nr) ? r : nr - 1);
        Xr[r] = x + ((size_t)(i & 3)*SEQ + c_pos[i >> 2])*DM;
      }
      acc8(A, Xr, Wi, DM, 0, j0, 4);
      fin8(A, Bi, j0, QH, DM, r0, nr);
    }
  } else {
    const float* W = Wi + (size_t)mat * DM * DM;
    const float* Bv = Bi + mat * DM;
    float* Y = (mat == 1) ? KH : VH;
    for (int ic = 0; ic < 8; ++ic) {
      const int r0 = ic * 8;
      float A[4][8] = {};
      const float* Xr[8];
#pragma unroll
      for (int r = 0; r < 8; ++r) Xr[r] = KV + (size_t)(r0 + r)*DM;
      acc8(A, Xr, W, DM, 0, j0, 4);
      fin8(A, Bv, j0, Y, DM, r0, 8);
    }
  }
}

// ---------------------------------------------------------------------------
// K5: attention (28 blocks; copy [4912,5912))
// ---------------------------------------------------------------------------
__global__ __launch_bounds__(256)
void k_attn(const float* __restrict__ x, const float* __restrict__ QH,
            const float* __restrict__ KH, const float* __restrict__ VH,
            float* __restrict__ OA, float* __restrict__ out)
{
  const int bid = blockIdx.x;
  if (bid >= 28) { copy4(x, out, 4912 + (bid - 28) * 4); return; }
  const int p = bid >> 2, b = bid & 3;
  const int h = threadIdx.x >> 6, lane = threadIdx.x & 63;
  const int ne = c_ne[p];
  const int qoff = (p*4+b)*DM + h*256 + lane;
  const float q0 = QH[qoff], q1 = QH[qoff+64], q2 = QH[qoff+128], q3 = QH[qoff+192];
  float sc0 = -1e30f, sc1 = -1e30f, sc2 = -1e30f;
  int k0 = 0, k1 = 0, k2 = 0;
  {
    k0 = (c_posE[p][0]*4 + b)*DM + h*256 + lane;
    float pr = q0*KH[k0] + q1*KH[k0+64] + q2*KH[k0+128] + q3*KH[k0+192];
#pragma unroll
    for (int off = 32; off >= 1; off >>= 1) pr += __shfl_xor(pr, off);
    sc0 = pr * 0.0625f;
  }
  if (ne > 1) {
    k1 = (c_posE[p][1]*4 + b)*DM + h*256 + lane;
    float pr = q0*KH[k1] + q1*KH[k1+64] + q2*KH[k1+128] + q3*KH[k1+192];
#pragma unroll
    for (int off = 32; off >= 1; off >>= 1) pr += __shfl_xor(pr, off);
    sc1 = pr * 0.0625f;
  }
  if (ne > 2) {
    k2 = (c_posE[p][2]*4 + b)*DM + h*256 + lane;
    float pr = q0*KH[k2] + q1*KH[k2+64] + q2*KH[k2+128] + q3*KH[k2+192];
#pragma unroll
    for (int off = 32; off >= 1; off >>= 1) pr += __shfl_xor(pr, off);
    sc2 = pr * 0.0625f;
  }
  const float m = fmaxf(sc0, fmaxf(sc1, sc2));
  const float e0 = expf(sc0 - m);
  const float e1 = (ne > 1) ? expf(sc1 - m) : 0.f;
  const float e2 = (ne > 2) ? expf(sc2 - m) : 0.f;
  const float inv = 1.f / (e0 + e1 + e2);
  const float A0 = e0*inv, A1 = e1*inv, A2 = e2*inv;
#pragma unroll
  for (int i = 0; i < 4; ++i) {
    float o = A0 * VH[k0 + i*64];
    if (ne > 1) o += A1 * VH[k1 + i*64];
    if (ne > 2) o += A2 * VH[k2 + i*64];
    OA[qoff + i*64] = o;
  }
}

// ---------------------------------------------------------------------------
// K6: O = OA @ attn_out_w^T + b (64 gemm blocks, chunk-looped;
//     copy [5912,6912))
// ---------------------------------------------------------------------------
__global__ __launch_bounds__(256)
void k_oproj(const float* __restrict__ x, const float* __restrict__ OA,
             const float* __restrict__ Wo, const float* __restrict__ Bo,
             float* __restrict__ O, float* __restrict__ out)
{
  const int bid = blockIdx.x;
  if (bid >= 64) { copy4(x, out, 5912 + (bid - 64) * 4); return; }
  const int j0 = bid * 16 + (threadIdx.x >> 6) * 4;
  for (int ic = 0; ic < 4; ++ic) {
    const int r0 = c_or0[ic], nr = c_onr[ic];
    float A[4][8] = {};
    const float* Xr[8];
#pragma unroll
    for (int r = 0; r < 8; ++r)
      Xr[r] = OA + (size_t)(r0 + ((r < nr) ? r : nr - 1)) * DM;
    acc8(A, Xr, Wo, DM, 0, j0, 4);
    fin8(A, Bo, j0, O, DM, r0, nr);
  }
}

// ---------------------------------------------------------------------------
// K7: UP = [O | x-rows] @ fus_w^T + b (K=2048; 64 gemm blocks, chunk-looped;
//     copy [6912,7712))
// ---------------------------------------------------------------------------
__global__ __launch_bounds__(256)
void k_fus(const float* __restrict__ x, const float* __restrict__ O,
           const float* __restrict__ Wf, const float* __restrict__ Bf,
           float* __restrict__ UP, float* __restrict__ out)
{
  const int bid = blockIdx.x;
  if (bid >= 64) { copy4(x, out, 6912 + (bid - 64) * 4); return; }
  const int j0 = bid * 16 + (threadIdx.x >> 6) * 4;
  for (int ic = 0; ic < 4; ++ic) {
    const int r0 = c_or0[ic], nr = c_onr[ic];
    float A[4][8] = {};
    const float* XrO[8]; const float* XrX[8];
#pragma unroll
    for (int r = 0; r < 8; ++r) {
      const int i = r0 + ((r < nr) ? r : nr - 1);
      XrO[r] = O + (size_t)i*DM;
      XrX[r] = x + ((size_t)(i & 3)*SEQ + c_pos[i >> 2])*DM;
    }
    acc8(A, XrO, Wf, 2048, 0, j0, 4);
    acc8(A, XrX, Wf, 2048, 1024, j0, 4);
    fin8(A, Bf, j0, UP, DM, r0, nr);
  }
}

// ---------------------------------------------------------------------------
// K8: final LN + scatter (28 blocks; copy [7712,8192))
// ---------------------------------------------------------------------------
__global__ __launch_bounds__(256)
void k_final(const float* __restrict__ x, const float* __restrict__ UP,
             const float* __restrict__ g, const float* __restrict__ bt,
             float* __restrict__ out)
{
  __shared__ float s1[4], s2[4];
  const int bid = blockIdx.x;
  if (bid >= 28) { copy4(x, out, 7712 + (bid - 28) * 4); return; }
  const int p = bid >> 2, b = bid & 3;
  const int j = threadIdx.x * 4;
  const int lane = threadIdx.x & 63, wv = threadIdx.x >> 6;
  const float4 v = *(const float4*)(UP + (size_t)bid*DM + j);
  float s = v.x+v.y+v.z+v.w;
  float q = v.x*v.x+v.y*v.y+v.z*v.z+v.w*v.w;
#pragma unroll
  for (int off = 32; off >= 1; off >>= 1) {
    s += __shfl_xor(s, off); q += __shfl_xor(q, off);
  }
  if (lane == 0) { s1[wv] = s; s2[wv] = q; }
  __syncthreads();
  const float ts = s1[0]+s1[1]+s1[2]+s1[3];
  const float tq = s2[0]+s2[1]+s2[2]+s2[3];
  const float m = ts * (1.f/1024.f);
  const float rs = rsqrtf(tq * (1.f/1024.f) - m*m + 1e-5f);
  const float* gg = g + j;
  const float* bb = bt + j;
  float4 o;
  o.x = (v.x-m)*rs*gg[0] + bb[0];
  o.y = (v.y-m)*rs*gg[1] + bb[1];
  o.z = (v.z-m)*rs*gg[2] + bb[2];
  o.w = (v.w-m)*rs*gg[3] + bb[3];
  *(float4*)(out + ((size_t)b*SEQ + c_pos[p])*DM + j) = o;
}

// ---------------------------------------------------------------------------
// Launch. Copy blocks (4 chunks each), total 2048 = 8192 chunks:
//   feats 260 | lat1 230 | ln 280 | lat2 230 | qkv 228 | attn 250
//   | oproj 250 | fus 200 | final 120
// ---------------------------------------------------------------------------
extern "C" void kernel_launch(void* const* d_in, const int* in_sizes, int n_in,
                              void* d_out, int out_size, void* d_ws, size_t ws_size,
                              hipStream_t stream)
{
  const float* x          = (const float*)d_in[0];
  const float* lt_w1      = (const float*)d_in[1];
  const float* lt_b1      = (const float*)d_in[2];
  const float* lt_ln_g    = (const float*)d_in[3];
  const float* lt_ln_b    = (const float*)d_in[4];
  const float* lt_w2      = (const float*)d_in[5];
  const float* lt_b2      = (const float*)d_in[6];
  const float* attn_in_w  = (const float*)d_in[7];
  const float* attn_in_b  = (const float*)d_in[8];
  const float* attn_out_w = (const float*)d_in[9];
  const float* attn_out_b = (const float*)d_in[10];
  const float* fus_w      = (const float*)d_in[11];
  const float* fus_b      = (const float*)d_in[12];
  const float* fus_ln_g   = (const float*)d_in[13];
  const float* fus_ln_b   = (const float*)d_in[14];
  float* out = (float*)d_out;
  float* ws  = (float*)d_ws;

  float* F  = ws;                  // 64 x 1024
  float* Hh = F  + 65536;          // 64 x 1024
  float* G  = Hh + 65536;          // 64 x 1024
  float* KV = G  + 65536;          // 64 x 1024
  float* QH = KV + 65536;          // 28 x 1024 (32 alloc)
  float* KH = QH + 32768;          // 64 x 1024
  float* VH = KH + 65536;          // 64 x 1024
  float* OA = VH + 65536;          // 28 x 1024
  float* O  = OA + 32768;          // 28 x 1024
  float* UP = O  + 32768;          // 28 x 1024

  k_feats<<<324, 256, 0, stream>>>(x, F, out);
  k_lat1 <<<422, 256, 0, stream>>>(x, F, lt_w1, lt_b1, Hh, out);
  k_ln   <<<344, 256, 0, stream>>>(x, Hh, lt_ln_g, lt_ln_b, G, out);
  k_lat2 <<<422, 256, 0, stream>>>(x, G, lt_w2, lt_b2, KV, out);
  k_qkv  <<<420, 256, 0, stream>>>(x, KV, attn_in_w, attn_in_b, QH, KH, VH, out);
  k_attn <<<278, 256, 0, stream>>>(x, QH, KH, VH, OA, out);
  k_oproj<<<314, 256, 0, stream>>>(x, OA, attn_out_w, attn_out_b, O, out);
  k_fus  <<<264, 256, 0, stream>>>(x, O, fus_w, fus_b, UP, out);
  k_final<<<148, 256, 0, stream>>>(x, UP, fus_ln_g, fus_ln_b, out);
}

// Round 11
// 97.950 us; speedup vs baseline: 1.9021x; 1.9021x over previous
//
#include <hip/hip_runtime.h>
#include <math.h>

// ---------------------------------------------------------------------------
// B=4, S=8192, D=1024, H=4, hd=256.
// Lattice positions {12,36,104,304,888,2592,7568}; 16 entries level-major
// (rows = e*4+b: L1 0..27, L2 28..51, L3 52..63).
//
// 9 kernels, stream-ordered (round-8 structure, round-8 grids). Surplus
// blocks copy a static slice of x->out (plain loads keep x L3-warm;
// nontemporal stores; skip the 28 chain-written rows).
// GEMMs: proven A[4][8] per-wave shape. NEW vs round 8: block = (4-col
// j-tile, chunk-group); the 4 waves take 4 DIFFERENT row-chunks x the SAME
// 4 W columns -> W lines shared via L1 -> weight HBM traffic ~200->~60 MB.
// ---------------------------------------------------------------------------

#define SEQ 8192
#define DM  1024

typedef float fx4 __attribute__((ext_vector_type(4)));

__device__ __constant__ int c_nodes[16][3] = {
  {0,2,4},{2,4,12},{4,12,36},{12,36,104},{36,104,304},{104,304,888},{304,888,2592},
  {0,0,0},{0,2,0},{0,2,4},{2,4,12},{4,12,36},{12,36,104},
  {0,0,0},{0,2,0},{0,2,4}};
__device__ __constant__ float c_wt[16][3] = {
  {1,1,1},{1,1,1},{1,1,1},{1,1,1},{1,1,1},{1,1,1},{1,1,1},
  {1,0,0},{1,1,0},{1,1,1},{1,2,3},{1,2,3},{1,2,3},
  {1,0,0},{1,1,0},{1,1,1}};
__device__ __constant__ float c_winv[16] = {
  1.f/3.f,1.f/3.f,1.f/3.f,1.f/3.f,1.f/3.f,1.f/3.f,1.f/3.f,
  1.f,0.5f,1.f/3.f,1.f/6.f,1.f/6.f,1.f/6.f,
  1.f,0.5f,1.f/3.f};
__device__ __constant__ int c_pos[7]  = {12,36,104,304,888,2592,7568};
__device__ __constant__ int c_ne[7]   = {1,2,2,2,3,3,3};
__device__ __constant__ int c_posE[7][3] = {
  {0,0,0},{1,7,0},{2,8,0},{3,9,0},{4,10,13},{5,11,14},{6,12,15}};

// 8-row chunks of the 64 entry-rows (levels don't cross chunks)
__device__ __constant__ int c_lr0[9]  = {0,8,16,24,28,36,44,52,60};
__device__ __constant__ int c_lnr[9]  = {8,8,8,4,8,8,8,8,4};
__device__ __constant__ int c_or0[4]  = {0,8,16,24};
__device__ __constant__ int c_onr[4]  = {8,8,8,4};

// ---------------------------------------------------------------------------
// copy 4 chunks (16 KB = 4 rows each) at c0; 16 loads in flight; stores
// skip the 28 chain-written rows.
// ---------------------------------------------------------------------------
__device__ __forceinline__ void copy4(const float* __restrict__ x,
                                      float* __restrict__ out, int c0)
{
  const fx4* __restrict__ src4 = (const fx4*)x;
  fx4* __restrict__ dst4 = (fx4*)out;
  const int tid = threadIdx.x;
  fx4 v[16]; size_t idx[16];
#pragma unroll
  for (int u = 0; u < 16; ++u) {
    const int c = c0 + (u >> 2), k = u & 3;
    idx[u] = (size_t)c * 1024 + (size_t)k * 256 + tid;
    v[u] = src4[idx[u]];
  }
#pragma unroll
  for (int u = 0; u < 16; ++u) {
    const int s = ((c0 + (u >> 2)) * 4 + (u & 3)) & (SEQ - 1);
    if (s==12 || s==36 || s==104 || s==304 || s==888 || s==2592 || s==7568)
      continue;
    __builtin_nontemporal_store(v[u], &dst4[idx[u]]);
  }
}

// ---------------------------------------------------------------------------
// GEMM core (proven shape): the calling wave owns 4 cols j0..j0+3 and 8 rows
// via pointer array; lanes over k (float4); runtime k-loop.
// ---------------------------------------------------------------------------
__device__ __forceinline__ void acc8(float (&A)[4][8],
                                     const float* const (&Xr)[8],
                                     const float* __restrict__ W,
                                     int Wld, int wcol, int j0, int T)
{
  const int lane = threadIdx.x & 63;
  for (int t = 0; t < T; ++t) {
    const int k = t * 256 + lane * 4;
    const float* wp = W + (size_t)j0 * Wld + wcol + k;
    const float4 w0 = *(const float4*)(wp);
    const float4 w1 = *(const float4*)(wp + Wld);
    const float4 w2 = *(const float4*)(wp + 2 * Wld);
    const float4 w3 = *(const float4*)(wp + 3 * Wld);
#pragma unroll
    for (int r = 0; r < 8; ++r) {
      const float4 xv = *(const float4*)(Xr[r] + k);
      A[0][r] += w0.x*xv.x + w0.y*xv.y + w0.z*xv.z + w0.w*xv.w;
      A[1][r] += w1.x*xv.x + w1.y*xv.y + w1.z*xv.z + w1.w*xv.w;
      A[2][r] += w2.x*xv.x + w2.y*xv.y + w2.z*xv.z + w2.w*xv.w;
      A[3][r] += w3.x*xv.x + w3.y*xv.y + w3.z*xv.z + w3.w*xv.w;
    }
  }
}

__device__ __forceinline__ void fin8(float (&A)[4][8],
                                     const float* __restrict__ Bv, int j0,
                                     float* __restrict__ Y, int ldy,
                                     int r0, int nr)
{
  const int lane = threadIdx.x & 63;
#pragma unroll
  for (int r = 0; r < 8; ++r) {
    float v0 = A[0][r], v1 = A[1][r], v2 = A[2][r], v3 = A[3][r];
#pragma unroll
    for (int off = 32; off >= 1; off >>= 1) {
      v0 += __shfl_xor(v0, off); v1 += __shfl_xor(v1, off);
      v2 += __shfl_xor(v2, off); v3 += __shfl_xor(v3, off);
    }
    if (lane == 0 && r < nr) {
      float* yr = Y + (size_t)(r0 + r) * ldy + j0;
      yr[0] = v0 + Bv[j0];     yr[1] = v1 + Bv[j0 + 1];
      yr[2] = v2 + Bv[j0 + 2]; yr[3] = v3 + Bv[j0 + 3];
    }
  }
}

// ---------------------------------------------------------------------------
// K0: F rows (64 blocks; copy chunks [0,1040))
// ---------------------------------------------------------------------------
__global__ __launch_bounds__(256)
void k_feats(const float* __restrict__ x, float* __restrict__ F,
             float* __restrict__ out)
{
  const int bid = blockIdx.x;
  if (bid >= 64) { copy4(x, out, 0 + (bid - 64) * 4); return; }
  const int e = bid >> 2, b = bid & 3;
  const int d = threadIdx.x * 4;
  float4 s = make_float4(0.f, 0.f, 0.f, 0.f);
#pragma unroll
  for (int n = 0; n < 3; ++n) {
    const float w = c_wt[e][n];
    const float4 v = *(const float4*)(x + ((size_t)b*SEQ + c_nodes[e][n])*DM + d);
    s.x += w*v.x; s.y += w*v.y; s.z += w*v.z; s.w += w*v.w;
  }
  const float inv = c_winv[e];
  s.x*=inv; s.y*=inv; s.z*=inv; s.w*=inv;
  *(float4*)(F + (size_t)bid*DM + d) = s;
}

// ---------------------------------------------------------------------------
// K1: H = F @ lt_w1^T + b1 (768 gemm blocks = lvl x 256 jt4; wave = chunk;
//     copy [1040,1960))
// ---------------------------------------------------------------------------
__global__ __launch_bounds__(256)
void k_lat1(const float* __restrict__ x, const float* __restrict__ F,
            const float* __restrict__ w1, const float* __restrict__ b1,
            float* __restrict__ Hh, float* __restrict__ out)
{
  const int bid = blockIdx.x;
  if (bid >= 768) { copy4(x, out, 1040 + (bid - 768) * 4); return; }
  const int lvl = bid >> 8, jt4 = bid & 255;
  const int j0 = jt4 * 4;
  const int wv = threadIdx.x >> 6;
  const int chlo = (lvl == 0) ? 0 : ((lvl == 1) ? 4 : 7);
  const int chhi = (lvl == 0) ? 4 : ((lvl == 1) ? 7 : 9);
  const int ch = chlo + wv;
  if (ch >= chhi) return;
  const int r0 = c_lr0[ch], nr = c_lnr[ch];
  float A[4][8] = {};
  const float* Xr[8];
#pragma unroll
  for (int r = 0; r < 8; ++r)
    Xr[r] = F + (size_t)(r0 + ((r < nr) ? r : nr - 1)) * DM;
  acc8(A, Xr, w1 + (size_t)lvl*DM*DM, DM, 0, j0, 4);
  fin8(A, b1 + lvl*DM, j0, Hh, DM, r0, nr);
}

// ---------------------------------------------------------------------------
// K2: G = GELU(LN(H)) (64 blocks; copy [1960,3080))
// ---------------------------------------------------------------------------
__global__ __launch_bounds__(256)
void k_ln(const float* __restrict__ x, const float* __restrict__ Hh,
          const float* __restrict__ lng, const float* __restrict__ lnb,
          float* __restrict__ G, float* __restrict__ out)
{
  __shared__ float s1[4], s2[4];
  const int bid = blockIdx.x;
  if (bid >= 64) { copy4(x, out, 1960 + (bid - 64) * 4); return; }
  const int lvl = (bid < 28) ? 0 : ((bid < 52) ? 1 : 2);
  const int j = threadIdx.x * 4;
  const int lane = threadIdx.x & 63, wv = threadIdx.x >> 6;
  const float4 v = *(const float4*)(Hh + (size_t)bid*DM + j);
  float s = v.x+v.y+v.z+v.w;
  float q = v.x*v.x+v.y*v.y+v.z*v.z+v.w*v.w;
#pragma unroll
  for (int off = 32; off >= 1; off >>= 1) {
    s += __shfl_xor(s, off); q += __shfl_xor(q, off);
  }
  if (lane == 0) { s1[wv] = s; s2[wv] = q; }
  __syncthreads();
  const float ts = s1[0]+s1[1]+s1[2]+s1[3];
  const float tq = s2[0]+s2[1]+s2[2]+s2[3];
  const float m = ts * (1.f/1024.f);
  const float rs = rsqrtf(tq * (1.f/1024.f) - m*m + 1e-5f);
  const float4 g4 = *(const float4*)(lng + (size_t)lvl*DM + j);
  const float4 b4 = *(const float4*)(lnb + (size_t)lvl*DM + j);
  const float t0 = (v.x-m)*rs*g4.x + b4.x;
  const float t1 = (v.y-m)*rs*g4.y + b4.y;
  const float t2 = (v.z-m)*rs*g4.z + b4.z;
  const float t3 = (v.w-m)*rs*g4.w + b4.w;
  const float kc = 0.70710678118654752f;
  float4 o;
  o.x = 0.5f*t0*(1.f+erff(t0*kc));
  o.y = 0.5f*t1*(1.f+erff(t1*kc));
  o.z = 0.5f*t2*(1.f+erff(t2*kc));
  o.w = 0.5f*t3*(1.f+erff(t3*kc));
  *(float4*)(G + (size_t)bid*DM + j) = o;
}

// ---------------------------------------------------------------------------
// K3: KV = G @ lt_w2^T + b2 (768 gemm blocks; wave = chunk; copy [3080,4000))
// ---------------------------------------------------------------------------
__global__ __launch_bounds__(256)
void k_lat2(const float* __restrict__ x, const float* __restrict__ G,
            const float* __restrict__ w2, const float* __restrict__ b2,
            float* __restrict__ KV, float* __restrict__ out)
{
  const int bid = blockIdx.x;
  if (bid >= 768) { copy4(x, out, 3080 + (bid - 768) * 4); return; }
  const int lvl = bid >> 8, jt4 = bid & 255;
  const int j0 = jt4 * 4;
  const int wv = threadIdx.x >> 6;
  const int chlo = (lvl == 0) ? 0 : ((lvl == 1) ? 4 : 7);
  const int chhi = (lvl == 0) ? 4 : ((lvl == 1) ? 7 : 9);
  const int ch = chlo + wv;
  if (ch >= chhi) return;
  const int r0 = c_lr0[ch], nr = c_lnr[ch];
  float A[4][8] = {};
  const float* Xr[8];
#pragma unroll
  for (int r = 0; r < 8; ++r)
    Xr[r] = G + (size_t)(r0 + ((r < nr) ? r : nr - 1)) * DM;
  acc8(A, Xr, w2 + (size_t)lvl*DM*DM, DM, 0, j0, 4);
  fin8(A, b2 + lvl*DM, j0, KV, DM, r0, nr);
}

// ---------------------------------------------------------------------------
// K4: Q/K/V projections (1280 gemm blocks = 5 groups x 256 jt4; wave = chunk;
//     copy [4000,4512))
// groups: 0 = Q (4 chunks of 28 x-rows); 1,2 = K halves; 3,4 = V halves
// ---------------------------------------------------------------------------
__global__ __launch_bounds__(256)
void k_qkv(const float* __restrict__ x, const float* __restrict__ KV,
           const float* __restrict__ Wi, const float* __restrict__ Bi,
           float* __restrict__ QH, float* __restrict__ KH,
           float* __restrict__ VH, float* __restrict__ out)
{
  const int bid = blockIdx.x;
  if (bid >= 1280) { copy4(x, out, 4000 + (bid - 1280) * 4); return; }
  const int grp = bid >> 8, jt4 = bid & 255;
  const int j0 = jt4 * 4;
  const int wv = threadIdx.x >> 6;
  float A[4][8] = {};
  const float* Xr[8];
  if (grp == 0) {
    const int r0 = c_or0[wv], nr = c_onr[wv];
#pragma unroll
    for (int r = 0; r < 8; ++r) {
      const int i = r0 + ((r < nr) ? r : nr - 1);
      Xr[r] = x + ((size_t)(i & 3)*SEQ + c_pos[i >> 2])*DM;
    }
    acc8(A, Xr, Wi, DM, 0, j0, 4);
    fin8(A, Bi, j0, QH, DM, r0, nr);
  } else {
    const int mat = (grp <= 2) ? 1 : 2;          // 1=K, 2=V
    const int half = (grp - 1) & 1;
    const int r0 = half * 32 + wv * 8;
#pragma unroll
    for (int r = 0; r < 8; ++r) Xr[r] = KV + (size_t)(r0 + r)*DM;
    acc8(A, Xr, Wi + (size_t)mat*DM*DM, DM, 0, j0, 4);
    fin8(A, Bi + mat*DM, j0, (mat == 1) ? KH : VH, DM, r0, 8);
  }
}

// ---------------------------------------------------------------------------
// K5: attention (28 blocks; copy [4512,5712))
// ---------------------------------------------------------------------------
__global__ __launch_bounds__(256)
void k_attn(const float* __restrict__ x, const float* __restrict__ QH,
            const float* __restrict__ KH, const float* __restrict__ VH,
            float* __restrict__ OA, float* __restrict__ out)
{
  const int bid = blockIdx.x;
  if (bid >= 28) { copy4(x, out, 4512 + (bid - 28) * 4); return; }
  const int p = bid >> 2, b = bid & 3;
  const int h = threadIdx.x >> 6, lane = threadIdx.x & 63;
  const int ne = c_ne[p];
  const int qoff = (p*4+b)*DM + h*256 + lane;
  const float q0 = QH[qoff], q1 = QH[qoff+64], q2 = QH[qoff+128], q3 = QH[qoff+192];
  float sc0 = -1e30f, sc1 = -1e30f, sc2 = -1e30f;
  int k0 = 0, k1 = 0, k2 = 0;
  {
    k0 = (c_posE[p][0]*4 + b)*DM + h*256 + lane;
    float pr = q0*KH[k0] + q1*KH[k0+64] + q2*KH[k0+128] + q3*KH[k0+192];
#pragma unroll
    for (int off = 32; off >= 1; off >>= 1) pr += __shfl_xor(pr, off);
    sc0 = pr * 0.0625f;
  }
  if (ne > 1) {
    k1 = (c_posE[p][1]*4 + b)*DM + h*256 + lane;
    float pr = q0*KH[k1] + q1*KH[k1+64] + q2*KH[k1+128] + q3*KH[k1+192];
#pragma unroll
    for (int off = 32; off >= 1; off >>= 1) pr += __shfl_xor(pr, off);
    sc1 = pr * 0.0625f;
  }
  if (ne > 2) {
    k2 = (c_posE[p][2]*4 + b)*DM + h*256 + lane;
    float pr = q0*KH[k2] + q1*KH[k2+64] + q2*KH[k2+128] + q3*KH[k2+192];
#pragma unroll
    for (int off = 32; off >= 1; off >>= 1) pr += __shfl_xor(pr, off);
    sc2 = pr * 0.0625f;
  }
  const float m = fmaxf(sc0, fmaxf(sc1, sc2));
  const float e0 = expf(sc0 - m);
  const float e1 = (ne > 1) ? expf(sc1 - m) : 0.f;
  const float e2 = (ne > 2) ? expf(sc2 - m) : 0.f;
  const float inv = 1.f / (e0 + e1 + e2);
  const float A0 = e0*inv, A1 = e1*inv, A2 = e2*inv;
#pragma unroll
  for (int i = 0; i < 4; ++i) {
    float o = A0 * VH[k0 + i*64];
    if (ne > 1) o += A1 * VH[k1 + i*64];
    if (ne > 2) o += A2 * VH[k2 + i*64];
    OA[qoff + i*64] = o;
  }
}

// ---------------------------------------------------------------------------
// K6: O = OA @ attn_out_w^T + b (256 gemm blocks; wave = chunk;
//     copy [5712,6712))
// ---------------------------------------------------------------------------
__global__ __launch_bounds__(256)
void k_oproj(const float* __restrict__ x, const float* __restrict__ OA,
             const float* __restrict__ Wo, const float* __restrict__ Bo,
             float* __restrict__ O, float* __restrict__ out)
{
  const int bid = blockIdx.x;
  if (bid >= 256) { copy4(x, out, 5712 + (bid - 256) * 4); return; }
  const int j0 = bid * 4;
  const int wv = threadIdx.x >> 6;
  const int r0 = c_or0[wv], nr = c_onr[wv];
  float A[4][8] = {};
  const float* Xr[8];
#pragma unroll
  for (int r = 0; r < 8; ++r)
    Xr[r] = OA + (size_t)(r0 + ((r < nr) ? r : nr - 1)) * DM;
  acc8(A, Xr, Wo, DM, 0, j0, 4);
  fin8(A, Bo, j0, O, DM, r0, nr);
}

// ---------------------------------------------------------------------------
// K7: UP = [O | x-rows] @ fus_w^T + b (K=2048; 256 gemm blocks; wave = chunk;
//     copy [6712,7712))
// ---------------------------------------------------------------------------
__global__ __launch_bounds__(256)
void k_fus(const float* __restrict__ x, const float* __restrict__ O,
           const float* __restrict__ Wf, const float* __restrict__ Bf,
           float* __restrict__ UP, float* __restrict__ out)
{
  const int bid = blockIdx.x;
  if (bid >= 256) { copy4(x, out, 6712 + (bid - 256) * 4); return; }
  const int j0 = bid * 4;
  const int wv = threadIdx.x >> 6;
  const int r0 = c_or0[wv], nr = c_onr[wv];
  float A[4][8] = {};
  const float* XrO[8]; const float* XrX[8];
#pragma unroll
  for (int r = 0; r < 8; ++r) {
    const int i = r0 + ((r < nr) ? r : nr - 1);
    XrO[r] = O + (size_t)i*DM;
    XrX[r] = x + ((size_t)(i & 3)*SEQ + c_pos[i >> 2])*DM;
  }
  acc8(A, XrO, Wf, 2048, 0, j0, 4);
  acc8(A, XrX, Wf, 2048, 1024, j0, 4);
  fin8(A, Bf, j0, UP, DM, r0, nr);
}

// ---------------------------------------------------------------------------
// K8: final LN + scatter (28 blocks; copy [7712,8192))
// ---------------------------------------------------------------------------
__global__ __launch_bounds__(256)
void k_final(const float* __restrict__ x, const float* __restrict__ UP,
             const float* __restrict__ g, const float* __restrict__ bt,
             float* __restrict__ out)
{
  __shared__ float s1[4], s2[4];
  const int bid = blockIdx.x;
  if (bid >= 28) { copy4(x, out, 7712 + (bid - 28) * 4); return; }
  const int p = bid >> 2, b = bid & 3;
  const int j = threadIdx.x * 4;
  const int lane = threadIdx.x & 63, wv = threadIdx.x >> 6;
  const float4 v = *(const float4*)(UP + (size_t)bid*DM + j);
  float s = v.x+v.y+v.z+v.w;
  float q = v.x*v.x+v.y*v.y+v.z*v.z+v.w*v.w;
#pragma unroll
  for (int off = 32; off >= 1; off >>= 1) {
    s += __shfl_xor(s, off); q += __shfl_xor(q, off);
  }
  if (lane == 0) { s1[wv] = s; s2[wv] = q; }
  __syncthreads();
  const float ts = s1[0]+s1[1]+s1[2]+s1[3];
  const float tq = s2[0]+s2[1]+s2[2]+s2[3];
  const float m = ts * (1.f/1024.f);
  const float rs = rsqrtf(tq * (1.f/1024.f) - m*m + 1e-5f);
  const float* gg = g + j;
  const float* bb = bt + j;
  float4 o;
  o.x = (v.x-m)*rs*gg[0] + bb[0];
  o.y = (v.y-m)*rs*gg[1] + bb[1];
  o.z = (v.z-m)*rs*gg[2] + bb[2];
  o.w = (v.w-m)*rs*gg[3] + bb[3];
  *(float4*)(out + ((size_t)b*SEQ + c_pos[p])*DM + j) = o;
}

// ---------------------------------------------------------------------------
// Launch. Copy blocks (4 chunks each), total 2048 = 8192 chunks:
//   feats 260 | lat1 230 | ln 280 | lat2 230 | qkv 128 | attn 300
//   | oproj 250 | fus 250 | final 120
// ---------------------------------------------------------------------------
extern "C" void kernel_launch(void* const* d_in, const int* in_sizes, int n_in,
                              void* d_out, int out_size, void* d_ws, size_t ws_size,
                              hipStream_t stream)
{
  const float* x          = (const float*)d_in[0];
  const float* lt_w1      = (const float*)d_in[1];
  const float* lt_b1      = (const float*)d_in[2];
  const float* lt_ln_g    = (const float*)d_in[3];
  const float* lt_ln_b    = (const float*)d_in[4];
  const float* lt_w2      = (const float*)d_in[5];
  const float* lt_b2      = (const float*)d_in[6];
  const float* attn_in_w  = (const float*)d_in[7];
  const float* attn_in_b  = (const float*)d_in[8];
  const float* attn_out_w = (const float*)d_in[9];
  const float* attn_out_b = (const float*)d_in[10];
  const float* fus_w      = (const float*)d_in[11];
  const float* fus_b      = (const float*)d_in[12];
  const float* fus_ln_g   = (const float*)d_in[13];
  const float* fus_ln_b   = (const float*)d_in[14];
  float* out = (float*)d_out;
  float* ws  = (float*)d_ws;

  float* F  = ws;                  // 64 x 1024
  float* Hh = F  + 65536;          // 64 x 1024
  float* G  = Hh + 65536;          // 64 x 1024
  float* KV = G  + 65536;          // 64 x 1024
  float* QH = KV + 65536;          // 28 x 1024 (32 alloc)
  float* KH = QH + 32768;          // 64 x 1024
  float* VH = KH + 65536;          // 64 x 1024
  float* OA = VH + 65536;          // 28 x 1024
  float* O  = OA + 32768;          // 28 x 1024
  float* UP = O  + 32768;          // 28 x 1024

  k_feats<<<324,  256, 0, stream>>>(x, F, out);
  k_lat1 <<<998,  256, 0, stream>>>(x, F, lt_w1, lt_b1, Hh, out);
  k_ln   <<<344,  256, 0, stream>>>(x, Hh, lt_ln_g, lt_ln_b, G, out);
  k_lat2 <<<998,  256, 0, stream>>>(x, G, lt_w2, lt_b2, KV, out);
  k_qkv  <<<1408, 256, 0, stream>>>(x, KV, attn_in_w, attn_in_b, QH, KH, VH, out);
  k_attn <<<328,  256, 0, stream>>>(x, QH, KH, VH, OA, out);
  k_oproj<<<506,  256, 0, stream>>>(x, OA, attn_out_w, attn_out_b, O, out);
  k_fus  <<<506,  256, 0, stream>>>(x, O, fus_w, fus_b, UP, out);
  k_final<<<148,  256, 0, stream>>>(x, UP, fus_ln_g, fus_ln_b, out);
}